// Round 4
// baseline (190.706 us; speedup 1.0000x reference)
//
#include <hip/hip_runtime.h>

typedef __attribute__((ext_vector_type(8))) __bf16 bf16x8;
typedef __attribute__((ext_vector_type(4))) float f32x4;

#define KC 256          // k-floats per chunk = 1KB per row => one wave-instr per row
#define NCH 4           // chunks per block: 1024 / 256
#define REC 12288       // record: accD[4096] | accNN[4096] | accAA[4096]
#define PBASE 4224      // dmat[4096] | Rn[64] | Ra[64]

__device__ __forceinline__ unsigned short f2bf(float x) {
    unsigned u = __float_as_uint(x);
    u += 0x7FFFu + ((u >> 16) & 1u);   // round-to-nearest-even
    return (unsigned short)(u >> 16);
}

// grid 400 = 200 t x 2 k-halves. Whole-wave-per-row loads: 1KB contiguous per instr.
__global__ __launch_bounds__(256, 2) void cl_partial(const float* __restrict__ feats,
                                                     float* __restrict__ ws)
{
    const int b   = blockIdx.x;          // 0..399
    const int t   = b >> 1;
    const int sl  = b & 1;
    const int tid = threadIdx.x;
    const int w   = tid >> 6;            // wave 0..3
    const int l   = tid & 63;
    const int r16 = tid & 15;
    const int kg  = (tid & 63) >> 4;

    __shared__ __align__(16) unsigned short lds[128][KC];   // 64KB: rows 0-63 = N, 64-127 = A

    const size_t kbase = (size_t)t * 2048 + (size_t)sl * 1024;

    f32x4 accD[4], accNN[4], accAA[4];
    const f32x4 zero = {0.f, 0.f, 0.f, 0.f};
    #pragma unroll
    for (int j = 0; j < 4; ++j) { accD[j] = zero; accNN[j] = zero; accAA[j] = zero; }

    const int rs = (r16 & 7) << 3;       // frag-read swizzle (row&7 == r16&7 for all frag rows)

    for (int c = 0; c < NCH; ++c) {
        // stage rows w*32 .. w*32+31; each row = one wave-wide float4 instr (1KB contiguous)
        #pragma unroll
        for (int h = 0; h < 2; ++h) {
            float4 v[16];
            #pragma unroll
            for (int rr = 0; rr < 16; ++rr) {
                const int row = w*32 + h*16 + rr;
                v[rr] = *(const float4*)(feats + (size_t)row * 409600 + kbase + c*KC + 4*l);
            }
            #pragma unroll
            for (int rr = 0; rr < 16; ++rr) {
                const int row = w*32 + h*16 + rr;
                ushort4 p;
                p.x = f2bf(v[rr].x); p.y = f2bf(v[rr].y);
                p.z = f2bf(v[rr].z); p.w = f2bf(v[rr].w);
                *(ushort4*)&lds[row][(4*l) ^ ((row & 7) << 3)] = p;
            }
        }
        __syncthreads();
        #pragma unroll
        for (int ks = 0; ks < 8; ++ks) {
            const int kb = ks*32 + kg*8;
            bf16x8 aN = *(const bf16x8*)&lds[w*16 + r16][kb ^ rs];
            bf16x8 aA = *(const bf16x8*)&lds[64 + w*16 + r16][kb ^ rs];
            #pragma unroll
            for (int jt = 0; jt < 4; ++jt) {
                bf16x8 bN = *(const bf16x8*)&lds[jt*16 + r16][kb ^ rs];
                bf16x8 bA = *(const bf16x8*)&lds[64 + jt*16 + r16][kb ^ rs];
                accD[jt]  = __builtin_amdgcn_mfma_f32_16x16x32_bf16(aN, bA, accD[jt],  0, 0, 0);
                accNN[jt] = __builtin_amdgcn_mfma_f32_16x16x32_bf16(aN, bN, accNN[jt], 0, 0, 0);
                accAA[jt] = __builtin_amdgcn_mfma_f32_16x16x32_bf16(aA, bA, accAA[jt], 0, 0, 0);
            }
        }
        __syncthreads();
    }

    // store raw partials to exclusive record (no atomics)
    float* rec = ws + PBASE + (size_t)b * REC;
    #pragma unroll
    for (int jt = 0; jt < 4; ++jt) {
        #pragma unroll
        for (int r = 0; r < 4; ++r) {
            const int ij = (w*16 + kg*4 + r) * 64 + jt*16 + r16;
            rec[ij]        = accD[jt][r];
            rec[4096 + ij] = accNN[jt][r];
            rec[8192 + ij] = accAA[jt][r];
        }
    }
}

// grid 200 (one block per t): sum 2 k-slices, diag -> n2/a2, hinge, accumulate.
__global__ __launch_bounds__(256) void cl_combine(float* __restrict__ ws)
{
    const int t   = blockIdx.x;
    const int tid = threadIdx.x;
    float* r0 = ws + PBASE + (size_t)(2*t)     * REC;
    float* r1 = ws + PBASE + (size_t)(2*t + 1) * REC;

    __shared__ float n2s[64], a2s[64];
    float cd[16], gn[16], ga[16];

    #pragma unroll
    for (int s = 0; s < 16; ++s) {
        const int ij = s*256 + tid;
        cd[s] = r0[ij]        + r1[ij];
        gn[s] = r0[4096 + ij] + r1[4096 + ij];
        ga[s] = r0[8192 + ij] + r1[8192 + ij];
        r0[4096 + ij] = gn[s];              // summed per-t Gram, for cl_final's column read
        r0[8192 + ij] = ga[s];
        if ((ij & 63) == (ij >> 6)) {       // diagonal: ij = 65*i
            const int i = ij >> 6;
            n2s[i] = gn[s];
            a2s[i] = ga[s];
            atomicAdd(&ws[4096 + i], gn[s]);   // Rn
            atomicAdd(&ws[4160 + i], ga[s]);   // Ra
        }
    }
    __syncthreads();

    #pragma unroll
    for (int s = 0; s < 16; ++s) {
        const int ij = s*256 + tid;
        float dist2 = fmaxf(n2s[ij >> 6] + a2s[ij & 63] - 2.f * cd[s], 0.f);
        float v = fmaxf(200.f - sqrtf(dist2), 0.f);
        atomicAdd(&ws[ij], v * v * 0.005f);    // dmat, 1/200
    }
}

__global__ __launch_bounds__(1024) void cl_final(const float* __restrict__ ws,
                                                 float* __restrict__ out)
{
    const int tid = threadIdx.x;
    __shared__ float wv[16];
    __shared__ int   wi[16];
    __shared__ int   sIdx;
    __shared__ float sG[16][64], sA[16][64];

    // argmin over dmat[4096], first-occurrence tie-break
    float bv = 3.4e38f; int bi = 1 << 30;
    #pragma unroll
    for (int u = 0; u < 4; ++u) {
        const int k = u*1024 + tid;
        float v = ws[k];
        if (v < bv) { bv = v; bi = k; }
    }
    #pragma unroll
    for (int off = 32; off > 0; off >>= 1) {
        float ov = __shfl_xor(bv, off);
        int   oi = __shfl_xor(bi, off);
        if (ov < bv || (ov == bv && oi < bi)) { bv = ov; bi = oi; }
    }
    if ((tid & 63) == 0) { wv[tid >> 6] = bv; wi[tid >> 6] = bi; }
    __syncthreads();
    if (tid == 0) {
        float fv = wv[0]; int fi = wi[0];
        for (int k = 1; k < 16; ++k)
            if (wv[k] < fv || (wv[k] == fv && wi[k] < fi)) { fv = wv[k]; fi = wi[k]; }
        sIdx = fi;
    }
    __syncthreads();
    const int idx = sIdx;
    const int mn = idx >> 6;
    const int ma = idx & 63;

    // Gram columns at (mn, ma): sum over t of the per-t summed Grams
    const int g = tid >> 6;     // 0..15 t-phase
    const int i = tid & 63;
    float an = 0.f, aa = 0.f;
    for (int t = g; t < 200; t += 16) {
        const float* r0 = ws + PBASE + (size_t)(2*t) * REC;
        an += r0[4096 + i*64 + mn];
        aa += r0[8192 + i*64 + ma];
    }
    sG[g][i] = an;
    sA[g][i] = aa;
    __syncthreads();

    if (tid < 64) {
        float gcn = 0.f, gca = 0.f;
        #pragma unroll
        for (int g2 = 0; g2 < 16; ++g2) { gcn += sG[g2][tid]; gca += sA[g2][tid]; }
        const float* Rn = ws + 4096;
        const float* Ra = ws + 4160;
        float tn = 0.f, ta = 0.f;
        if (tid != mn) tn = Rn[tid] + Rn[mn] - 2.f * gcn;
        if (tid != ma) ta = Ra[tid] + Ra[ma] - 2.f * gca;
        float s = tn + ta;
        #pragma unroll
        for (int off = 32; off > 0; off >>= 1) s += __shfl_xor(s, off);
        if (tid == 0)
            out[0] = 0.001f * ws[idx] + s * (1.f / 12800.f);   // /(200*64)
    }
}

extern "C" void kernel_launch(void* const* d_in, const int* in_sizes, int n_in,
                              void* d_out, int out_size, void* d_ws, size_t ws_size,
                              hipStream_t stream)
{
    const float* feats = (const float*)d_in[0];
    float* out = (float*)d_out;
    float* ws  = (float*)d_ws;

    hipMemsetAsync(d_ws, 0, PBASE * sizeof(float), stream);
    cl_partial<<<dim3(400), dim3(256), 0, stream>>>(feats, ws);
    cl_combine<<<dim3(200), dim3(256), 0, stream>>>(ws);
    cl_final<<<dim3(1), dim3(1024), 0, stream>>>(ws, out);
}

// Round 5
// 103.805 us; speedup vs baseline: 1.8372x; 1.8372x over previous
//
#include <hip/hip_runtime.h>

typedef __attribute__((ext_vector_type(8))) __bf16 bf16x8;
typedef __attribute__((ext_vector_type(4))) float f32x4;
typedef unsigned long long u64;

#define KC 256             // k-floats per LDS chunk = 1KB per row => one wave-instr per row
#define NCH 2              // chunks per slice: 512 / 256
#define REC 12288          // record: accD[4096] | accNN[4096] | accAA[4096]
#define OFF_N2T 64
#define OFF_A2T 12864
#define OFF_DP  25664      // dpart[200][4096]
#define OFF_REC 844864     // 800 records

__device__ __forceinline__ unsigned short f2bf(float x) {
    unsigned u = __float_as_uint(x);
    u += 0x7FFFu + ((u >> 16) & 1u);   // round-to-nearest-even
    return (unsigned short)(u >> 16);
}

// grid 800 = 200 t x 4 K-slices(512). Whole-wave-per-row loads: 1KB contiguous/instr.
__global__ __launch_bounds__(256, 2) void cl_partial(const float* __restrict__ feats,
                                                     float* __restrict__ ws)
{
    const int b   = blockIdx.x;          // 0..799
    const int t   = b >> 2;
    const int sl  = b & 3;
    const int tid = threadIdx.x;
    const int w   = tid >> 6;            // wave 0..3
    const int l   = tid & 63;
    const int r16 = tid & 15;
    const int kg  = (tid & 63) >> 4;

    __shared__ __align__(16) unsigned short lds[128][KC];   // 64KB: rows 0-63 N, 64-127 A

    const size_t kbase = (size_t)t * 2048 + (size_t)sl * 512;

    f32x4 accD[4], accNN[4], accAA[4];
    const f32x4 zero = {0.f, 0.f, 0.f, 0.f};
    #pragma unroll
    for (int j = 0; j < 4; ++j) { accD[j] = zero; accNN[j] = zero; accAA[j] = zero; }

    const int rs = (r16 & 7) << 3;       // frag-read swizzle (frag row & 7 == r16 & 7)

    for (int c = 0; c < NCH; ++c) {
        #pragma unroll
        for (int h = 0; h < 2; ++h) {
            float4 v[16];
            #pragma unroll
            for (int rr = 0; rr < 16; ++rr) {
                const int row = w*32 + h*16 + rr;
                v[rr] = *(const float4*)(feats + (size_t)row * 409600 + kbase + c*KC + 4*l);
            }
            #pragma unroll
            for (int rr = 0; rr < 16; ++rr) {
                const int row = w*32 + h*16 + rr;
                ushort4 p;
                p.x = f2bf(v[rr].x); p.y = f2bf(v[rr].y);
                p.z = f2bf(v[rr].z); p.w = f2bf(v[rr].w);
                *(ushort4*)&lds[row][(4*l) ^ ((row & 7) << 3)] = p;
            }
        }
        __syncthreads();
        #pragma unroll
        for (int ks = 0; ks < 8; ++ks) {
            const int kb = ks*32 + kg*8;
            bf16x8 aN = *(const bf16x8*)&lds[w*16 + r16][kb ^ rs];
            bf16x8 aA = *(const bf16x8*)&lds[64 + w*16 + r16][kb ^ rs];
            #pragma unroll
            for (int jt = 0; jt < 4; ++jt) {
                bf16x8 bN = *(const bf16x8*)&lds[jt*16 + r16][kb ^ rs];
                bf16x8 bA = *(const bf16x8*)&lds[64 + jt*16 + r16][kb ^ rs];
                accD[jt]  = __builtin_amdgcn_mfma_f32_16x16x32_bf16(aN, bA, accD[jt],  0, 0, 0);
                accNN[jt] = __builtin_amdgcn_mfma_f32_16x16x32_bf16(aN, bN, accNN[jt], 0, 0, 0);
                accAA[jt] = __builtin_amdgcn_mfma_f32_16x16x32_bf16(aA, bA, accAA[jt], 0, 0, 0);
            }
        }
        __syncthreads();
    }

    float* rec = ws + OFF_REC + (size_t)b * REC;
    #pragma unroll
    for (int jt = 0; jt < 4; ++jt) {
        #pragma unroll
        for (int r = 0; r < 4; ++r) {
            const int ij = (w*16 + kg*4 + r) * 64 + jt*16 + r16;
            rec[ij]        = accD[jt][r];
            rec[4096 + ij] = accNN[jt][r];
            rec[8192 + ij] = accAA[jt][r];
        }
    }
}

// grid 200 (one block per t): sum 4 slices, diag->n2/a2, hinge -> exclusive dpart strip.
__global__ __launch_bounds__(256) void cl_combine(float* __restrict__ ws)
{
    const int t   = blockIdx.x;
    const int tid = threadIdx.x;
    float*       r0 = ws + OFF_REC + (size_t)(4*t)     * REC;
    const float* r1 = ws + OFF_REC + (size_t)(4*t + 1) * REC;
    const float* r2 = ws + OFF_REC + (size_t)(4*t + 2) * REC;
    const float* r3 = ws + OFF_REC + (size_t)(4*t + 3) * REC;

    __shared__ float n2s[64], a2s[64];
    float cd[16];

    #pragma unroll
    for (int s = 0; s < 16; ++s) {
        const int ij = s*256 + tid;
        cd[s]    = r0[ij]        + r1[ij]        + r2[ij]        + r3[ij];
        float gn = r0[4096 + ij] + r1[4096 + ij] + r2[4096 + ij] + r3[4096 + ij];
        float ga = r0[8192 + ij] + r1[8192 + ij] + r2[8192 + ij] + r3[8192 + ij];
        r0[4096 + ij] = gn;                 // per-t summed Gram for cl_final columns
        r0[8192 + ij] = ga;
        if ((ij & 63) == (ij >> 6)) {       // diagonal
            const int i = ij >> 6;
            n2s[i] = gn;
            a2s[i] = ga;
            ws[OFF_N2T + t*64 + i] = gn;
            ws[OFF_A2T + t*64 + i] = ga;
        }
    }
    __syncthreads();

    float* dp = ws + OFF_DP + (size_t)t * 4096;
    #pragma unroll
    for (int s = 0; s < 16; ++s) {
        const int ij = s*256 + tid;
        float dist2 = fmaxf(n2s[ij >> 6] + a2s[ij & 63] - 2.f * cd[s], 0.f);
        float v = fmaxf(200.f - sqrtf(dist2), 0.f);
        dp[ij] = v * v * 0.005f;            // 1/200
    }
}

// grid 16: sum dpart over t per ij, then packed-key argmin (16 atomics total).
__global__ __launch_bounds__(256) void cl_reduce(float* __restrict__ ws)
{
    const int tid = threadIdx.x;
    const int ij  = blockIdx.x * 256 + tid;
    const float* dp = ws + OFF_DP;

    float s = 0.f;
    for (int t = 0; t < 200; ++t) s += dp[(size_t)t * 4096 + ij];

    u64 key = ((u64)__float_as_uint(s) << 12) | (unsigned)ij;   // s>=0: bits order-preserving
    #pragma unroll
    for (int off = 32; off > 0; off >>= 1) {
        u64 o = __shfl_xor(key, off);
        key = o < key ? o : key;
    }
    __shared__ u64 wmin[4];
    if ((tid & 63) == 0) wmin[tid >> 6] = key;
    __syncthreads();
    if (tid == 0) {
        u64 m = wmin[0];
        for (int k = 1; k < 4; ++k) m = wmin[k] < m ? wmin[k] : m;
        atomicMin((u64*)ws, m);
    }
}

__global__ __launch_bounds__(1024) void cl_final(const float* __restrict__ ws,
                                                 float* __restrict__ out)
{
    const int tid = threadIdx.x;
    const u64 key = *(const u64*)ws;
    const int idx = (int)(key & 0xFFF);
    const float dmin = __uint_as_float((unsigned)(key >> 12));
    const int mn = idx >> 6;
    const int ma = idx & 63;

    __shared__ float sG[16][64], sA[16][64], sRn[16][64], sRa[16][64];
    __shared__ float GcnF[64], GcaF[64], RnF[64], RaF[64];

    const int g = tid >> 6;     // 0..15 t-phase
    const int i = tid & 63;
    float an = 0.f, aa = 0.f, rn = 0.f, ra = 0.f;
    for (int t = g; t < 200; t += 16) {
        const float* r0 = ws + OFF_REC + (size_t)(4*t) * REC;
        an += r0[4096 + i*64 + mn];
        aa += r0[8192 + i*64 + ma];
        rn += ws[OFF_N2T + t*64 + i];
        ra += ws[OFF_A2T + t*64 + i];
    }
    sG[g][i] = an; sA[g][i] = aa; sRn[g][i] = rn; sRa[g][i] = ra;
    __syncthreads();

    if (tid < 64) {
        float gcn = 0.f, gca = 0.f, rnf = 0.f, raf = 0.f;
        #pragma unroll
        for (int g2 = 0; g2 < 16; ++g2) {
            gcn += sG[g2][tid]; gca += sA[g2][tid];
            rnf += sRn[g2][tid]; raf += sRa[g2][tid];
        }
        GcnF[tid] = gcn; GcaF[tid] = gca; RnF[tid] = rnf; RaF[tid] = raf;
    }
    __syncthreads();

    if (tid < 64) {
        float tn = 0.f, ta = 0.f;
        if (tid != mn) tn = RnF[tid] + RnF[mn] - 2.f * GcnF[tid];
        if (tid != ma) ta = RaF[tid] + RaF[ma] - 2.f * GcaF[tid];
        float s = tn + ta;
        #pragma unroll
        for (int off = 32; off > 0; off >>= 1) s += __shfl_xor(s, off);
        if (tid == 0)
            out[0] = 0.001f * dmin + s * (1.f / 12800.f);   // /(200*64)
    }
}

extern "C" void kernel_launch(void* const* d_in, const int* in_sizes, int n_in,
                              void* d_out, int out_size, void* d_ws, size_t ws_size,
                              hipStream_t stream)
{
    const float* feats = (const float*)d_in[0];
    float* out = (float*)d_out;
    float* ws  = (float*)d_ws;

    hipMemsetAsync(d_ws, 0xFF, 8, stream);   // argmin key = u64 max
    cl_partial<<<dim3(800), dim3(256), 0, stream>>>(feats, ws);
    cl_combine<<<dim3(200), dim3(256), 0, stream>>>(ws);
    cl_reduce<<<dim3(16), dim3(256), 0, stream>>>(ws);
    cl_final<<<dim3(1), dim3(1024), 0, stream>>>(ws, out);
}